// Round 5
// baseline (151.523 us; speedup 1.0000x reference)
//
#include <hip/hip_runtime.h>
#include <hip/hip_bf16.h>
#include <stdint.h>

// Problem constants
#define KK 4
#define BB 16
#define LL 4096
#define DD 512
#define HH 128

typedef __attribute__((ext_vector_type(8))) short bf16x8;
typedef __attribute__((ext_vector_type(4))) float f32x4;
typedef __attribute__((ext_vector_type(4))) unsigned int u32x4;

__device__ __forceinline__ unsigned int pack_bf16(float lo, float hi) {
  unsigned int a = __float_as_uint(lo);
  unsigned int b = __float_as_uint(hi);
  a = (a + 0x7FFFu + ((a >> 16) & 1u)) >> 16;   // RNE f32->bf16
  b = (b + 0x7FFFu + ((b >> 16) & 1u)) >> 16;
  return a | (b << 16);
}

// Raw barrier: LDS-ordering only. Deliberately NOT __syncthreads() — that
// lowers with s_waitcnt vmcnt(0) and would drain the in-flight next-tile
// global loads (the R4 bottleneck). lgkmcnt(0) orders ds_write publish.
__device__ __forceinline__ void bar_lds() {
  __builtin_amdgcn_sched_barrier(0);
  asm volatile("s_waitcnt lgkmcnt(0)" ::: "memory");
  __builtin_amdgcn_s_barrier();
  __builtin_amdgcn_sched_barrier(0);
}

// ---------------- kernel 0a: q_bias = W_q @ vq + ln_b ----------------
__global__ void qbias_kernel(const float* __restrict__ ln_w,
                             const float* __restrict__ ln_b,
                             const float* __restrict__ vq,
                             float* __restrict__ qb) {
  int h = threadIdx.x;
  if (h < HH) {
    float acc = ln_b[h];
    const float* wq = ln_w + (size_t)h * (DD + HH) + DD;
    for (int j = 0; j < HH; ++j) acc = fmaf(wq[j], vq[j], acc);
    qb[h] = acc;
  }
}

// ---------------- kernel 0b: W_h -> fragment-ordered bf16 (natural d) ----
// Chunk gid = (ks*8 + nt)*64 + lane holds 8 bf16 (MFMA B-fragment):
//   element j: W[nt*16 + (lane&15)][ks*32 + (lane>>4)*8 + j]
__global__ void wf_kernel(const float* __restrict__ ln_w,
                          unsigned int* __restrict__ wf) {
  int gid = blockIdx.x * 256 + threadIdx.x;   // 0..8191
  int ks = gid >> 9;
  int nt = (gid >> 6) & 7;
  int lane = gid & 63;
  int h = nt * 16 + (lane & 15);
  int d0 = ks * 32 + (lane >> 4) * 8;
  const float* src = ln_w + (size_t)h * (DD + HH) + d0;
  u32x4 v;
  v.x = pack_bf16(src[0], src[1]);
  v.y = pack_bf16(src[2], src[3]);
  v.z = pack_bf16(src[4], src[5]);
  v.w = pack_bf16(src[6], src[7]);
  *(u32x4*)(wf + (size_t)gid * 4) = v;
}

// ---------------- main fused kernel ----------------
// 256 blocks x 512 threads (1 block/CU, 8 waves), persistent over 32 tiles
// of 8 positions. W split by h across waves (regs). A tile double-buffered
// as bf16 in LDS (2x32KB), reg-staged: loads issued at tile start, packed +
// ds_written at tile end; raw barriers keep them in flight throughout.
// A rows: row = pos*4 + k (XOR-swizzled by (row&7)<<4). MFMA M-subtiles
// st=0,1 cover rows st*16..+15 -> C/D: pos = st*4 + (lane>>4), k = reg j.
__global__ __launch_bounds__(512) void agg_main(
    const float* __restrict__ hs, const unsigned int* __restrict__ wf,
    const float* __restrict__ qb, const float* __restrict__ vw,
    float* __restrict__ out) {
  extern __shared__ char smem[];
  char* abuf = smem;                             // 2 x 32768 B
  f32x4* spv = (f32x4*)(smem + 65536);           // [8 pos][8 wv] partial s (k in vec)

  const int tid = threadIdx.x;
  const int lane = tid & 63;
  const int wv = tid >> 6;            // 0..7
  const int r = lane & 15;
  const int cg = lane >> 4;

  const int b = blockIdx.x >> 4;
  const int l0b = (blockIdx.x & 15) << 8;        // 256 l per block, 32 tiles of 8

  // ---- W fragments for nt = wv (h in [wv*16, wv*16+16)) ----
  bf16x8 wreg[16];
#pragma unroll
  for (int ks = 0; ks < 16; ++ks)
    wreg[ks] = *(const bf16x8*)(wf + ((size_t)((ks * 8 + wv) * 64 + lane)) * 4);

  const float qbr = qb[wv * 16 + r];
  const float vwr = vw[wv * 16 + r];

  // ---- staging helpers (chunk i: row = i*8+wv, d0 = (lane ^ wv)*8) ----
  f32x4 sv[8];
  auto issue_stage = [&](int l0) {
#pragma unroll
    for (int i = 0; i < 4; ++i) {
      int row = i * 8 + wv;
      int k = row & 3, pos = row >> 2;
      int d0 = (lane ^ (row & 7)) * 8;
      const float* p = hs + (((size_t)(k * BB + b)) * LL + l0 + pos) * DD + d0;
      sv[i * 2]     = *(const f32x4*)(p);
      sv[i * 2 + 1] = *(const f32x4*)(p + 4);
    }
  };
  auto write_stage = [&](char* dst) {
#pragma unroll
    for (int i = 0; i < 4; ++i) {
      u32x4 pk;
      pk.x = pack_bf16(sv[i * 2].x, sv[i * 2].y);
      pk.y = pack_bf16(sv[i * 2].z, sv[i * 2].w);
      pk.z = pack_bf16(sv[i * 2 + 1].x, sv[i * 2 + 1].y);
      pk.w = pack_bf16(sv[i * 2 + 1].z, sv[i * 2 + 1].w);
      *(u32x4*)(dst + i * 8192 + tid * 16) = pk;   // physical = logical ^ ((row&7)<<4)
    }
  };

  // ---- prologue: stage tile 0 ----
  issue_stage(l0b);
  write_stage(abuf);
  bar_lds();

  for (int t = 0; t < 32; ++t) {
    const int l0 = l0b + t * 8;
    char* cur = abuf + (t & 1) * 32768;
    char* nxt = abuf + ((t & 1) ^ 1) * 32768;

    // issue next tile's global loads NOW; raw barriers keep them in flight
    if (t < 31) issue_stage(l0 + 8);

    // ---- GEMM: 2 M-subtiles x 16 K-steps ----
    f32x4 acc0 = {0.f, 0.f, 0.f, 0.f};
    f32x4 acc1 = {0.f, 0.f, 0.f, 0.f};
    const int swz = (r & 7) << 4;     // rows st*16+r share (row&7)=r&7
#pragma unroll
    for (int ks = 0; ks < 16; ++ks) {
      int inner = (ks * 64 + cg * 16) ^ swz;
      bf16x8 a0 = *(const bf16x8*)(cur + r * 1024 + inner);
      bf16x8 a1 = *(const bf16x8*)(cur + (16 + r) * 1024 + inner);
      acc0 = __builtin_amdgcn_mfma_f32_16x16x32_bf16(a0, wreg[ks], acc0, 0, 0, 0);
      acc1 = __builtin_amdgcn_mfma_f32_16x16x32_bf16(a1, wreg[ks], acc1, 0, 0, 0);
    }

    // ---- partial scores: p = vw[h]*tanh(z + qb[h]), reduce over 16 h ----
    float ps[8];
#pragma unroll
    for (int st = 0; st < 2; ++st) {
      f32x4 acc = st ? acc1 : acc0;
#pragma unroll
      for (int j = 0; j < 4; ++j) {
        float z = acc[j] + qbr;
        z = fminf(15.f, fmaxf(-15.f, z));
        float e = __expf(-2.f * z);
        float th = (1.f - e) * __builtin_amdgcn_rcpf(1.f + e);
        ps[st * 4 + j] = vwr * th;
      }
    }
#pragma unroll
    for (int m = 1; m < 16; m <<= 1) {
#pragma unroll
      for (int q = 0; q < 8; ++q) ps[q] += __shfl_xor(ps[q], m, 64);
    }
    if (r == 0) {
      f32x4 v0 = {ps[0], ps[1], ps[2], ps[3]};
      f32x4 v1 = {ps[4], ps[5], ps[6], ps[7]};
      spv[cg * 8 + wv] = v0;          // pos = cg
      spv[(4 + cg) * 8 + wv] = v1;    // pos = 4 + cg
    }
    bar_lds();                        // B1: spv published (loads stay in flight)

    // ---- per-thread softmax over k for pos = wv (broadcast spv reads) ----
    // mask dropped: uniform per-(b,l) shift is softmax-invariant
    float a0, a1, a2, a3;
    {
      f32x4 s = spv[wv * 8 + 0];
#pragma unroll
      for (int w2 = 1; w2 < 8; ++w2) s += spv[wv * 8 + w2];
      float mx = fmaxf(fmaxf(s.x, s.y), fmaxf(s.z, s.w));
      float e0 = __expf(s.x - mx), e1 = __expf(s.y - mx);
      float e2 = __expf(s.z - mx), e3 = __expf(s.w - mx);
      float inv = __builtin_amdgcn_rcpf(e0 + e1 + e2 + e3);
      a0 = e0 * inv; a1 = e1 * inv; a2 = e2 * inv; a3 = e3 * inv;
    }

    // ---- weighted sum: wave wv handles pos = wv; x[d] = sum_k a_k*hs_k[d] ----
    {
      float x[8];
#pragma unroll
      for (int j = 0; j < 8; ++j) x[j] = 0.f;
#pragma unroll
      for (int k = 0; k < 4; ++k) {
        int row = wv * 4 + k;
        float ak = k == 0 ? a0 : (k == 1 ? a1 : (k == 2 ? a2 : a3));
        u32x4 u = *(const u32x4*)(cur + row * 1024 + ((lane * 16) ^ ((row & 7) << 4)));
        x[0] = fmaf(ak, __uint_as_float(u.x << 16), x[0]);
        x[1] = fmaf(ak, __uint_as_float(u.x & 0xffff0000u), x[1]);
        x[2] = fmaf(ak, __uint_as_float(u.y << 16), x[2]);
        x[3] = fmaf(ak, __uint_as_float(u.y & 0xffff0000u), x[3]);
        x[4] = fmaf(ak, __uint_as_float(u.z << 16), x[4]);
        x[5] = fmaf(ak, __uint_as_float(u.z & 0xffff0000u), x[5]);
        x[6] = fmaf(ak, __uint_as_float(u.w << 16), x[6]);
        x[7] = fmaf(ak, __uint_as_float(u.w & 0xffff0000u), x[7]);
      }
      float* ob = out + (((size_t)b) * LL + l0 + wv) * DD + lane * 8;
      f32x4 o0 = {x[0], x[1], x[2], x[3]};
      f32x4 o1 = {x[4], x[5], x[6], x[7]};
      *(f32x4*)(ob) = o0;
      *(f32x4*)(ob + 4) = o1;
    }

    // ---- publish next tile's buffer (waits only on sv's counted vmcnt) ----
    if (t < 31) write_stage(nxt);
    bar_lds();                        // B2: buffer published
  }
}

extern "C" void kernel_launch(void* const* d_in, const int* in_sizes, int n_in,
                              void* d_out, int out_size, void* d_ws, size_t ws_size,
                              hipStream_t stream) {
  const float* hs   = (const float*)d_in[0];
  // d_in[1] = mask (int32) — unused: softmax over k is invariant to the
  // per-(b,l) uniform -1e4 shift, so the mask cannot affect x.
  const float* ln_w = (const float*)d_in[2];
  const float* ln_b = (const float*)d_in[3];
  const float* v_w  = (const float*)d_in[4];
  const float* vq   = (const float*)d_in[5];
  float* out = (float*)d_out;

  unsigned int* wf = (unsigned int*)d_ws;          // 128KB fragment-ordered bf16 W_h
  float* qb = (float*)((char*)d_ws + 131072);      // 512B q_bias

  qbias_kernel<<<1, 128, 0, stream>>>(ln_w, ln_b, vq, qb);
  wf_kernel<<<32, 256, 0, stream>>>(ln_w, wf);
  agg_main<<<256, 512, 66560, stream>>>(hs, wf, qb, v_w, out);
}

// Round 6
// 151.445 us; speedup vs baseline: 1.0005x; 1.0005x over previous
//
#include <hip/hip_runtime.h>
#include <hip/hip_bf16.h>
#include <stdint.h>

// Problem constants
#define KK 4
#define BB 16
#define LL 4096
#define DD 512
#define HH 128

typedef __attribute__((ext_vector_type(8))) short bf16x8;
typedef __attribute__((ext_vector_type(4))) float f32x4;
typedef __attribute__((ext_vector_type(4))) unsigned int u32x4;

__device__ __forceinline__ unsigned int pack_bf16(float lo, float hi) {
  unsigned int a = __float_as_uint(lo);
  unsigned int b = __float_as_uint(hi);
  a = (a + 0x7FFFu + ((a >> 16) & 1u)) >> 16;   // RNE f32->bf16
  b = (b + 0x7FFFu + ((b >> 16) & 1u)) >> 16;
  return a | (b << 16);
}

// Raw barrier: LDS-ordering only (global loads stay in flight across it).
__device__ __forceinline__ void bar_lds() {
  __builtin_amdgcn_sched_barrier(0);
  asm volatile("s_waitcnt lgkmcnt(0)" ::: "memory");
  __builtin_amdgcn_s_barrier();
  __builtin_amdgcn_sched_barrier(0);
}

// x += row_shr:N (x) on the VALU pipe; rows of 16 lanes; 0-fill at row edge.
template <int N>
__device__ __forceinline__ float dpp_shr_add(float x) {
  int y = __builtin_amdgcn_update_dpp(0, __float_as_int(x), 0x110 | N, 0xF, 0xF,
                                      true);
  return x + __int_as_float(y);
}

// ---------------- kernel 0a: q_bias = W_q @ vq + ln_b ----------------
__global__ void qbias_kernel(const float* __restrict__ ln_w,
                             const float* __restrict__ ln_b,
                             const float* __restrict__ vq,
                             float* __restrict__ qb) {
  int h = threadIdx.x;
  if (h < HH) {
    float acc = ln_b[h];
    const float* wq = ln_w + (size_t)h * (DD + HH) + DD;
    for (int j = 0; j < HH; ++j) acc = fmaf(wq[j], vq[j], acc);
    qb[h] = acc;
  }
}

// ---------------- kernel 0b: W_h -> fragment-ordered bf16 (natural d) ----
// Chunk gid = (ks*8 + nt)*64 + lane holds 8 bf16 (MFMA B-fragment):
//   element j: W[nt*16 + (lane&15)][ks*32 + (lane>>4)*8 + j]
__global__ void wf_kernel(const float* __restrict__ ln_w,
                          unsigned int* __restrict__ wf) {
  int gid = blockIdx.x * 256 + threadIdx.x;   // 0..8191
  int ks = gid >> 9;
  int nt = (gid >> 6) & 7;
  int lane = gid & 63;
  int h = nt * 16 + (lane & 15);
  int d0 = ks * 32 + (lane >> 4) * 8;
  const float* src = ln_w + (size_t)h * (DD + HH) + d0;
  u32x4 v;
  v.x = pack_bf16(src[0], src[1]);
  v.y = pack_bf16(src[2], src[3]);
  v.z = pack_bf16(src[4], src[5]);
  v.w = pack_bf16(src[6], src[7]);
  *(u32x4*)(wf + (size_t)gid * 4) = v;
}

// ---------------- main fused kernel ----------------
// 256 blocks x 512 threads (1 block/CU, 8 waves), persistent over 32 tiles
// of 8 positions. A tile double-buffered as bf16 in LDS (2x32KB), reg-staged.
// GEMM cell map: wave wv -> M-subtile st = wv&1, N-tiles nt = {2p, 2p+1},
// p = wv>>1  (1 A-read + 2 MFMA per K-step; W = 32 frags = 128 VGPR).
// A rows: row = pos*4 + k (XOR-swizzled by (row&7)<<4).
// C/D: pos = st*4 + (lane>>4), k = reg j -> softmax k fully in-register.
__global__ __launch_bounds__(512) void agg_main(
    const float* __restrict__ hs, const unsigned int* __restrict__ wf,
    const float* __restrict__ qb, const float* __restrict__ vw,
    float* __restrict__ out) {
  extern __shared__ char smem[];
  char* abuf = smem;                             // 2 x 32768 B
  f32x4* spv = (f32x4*)(smem + 65536);           // [8 pos][4 contrib] (k in vec)

  const int tid = threadIdx.x;
  const int lane = tid & 63;
  const int wv = tid >> 6;            // 0..7
  const int r = lane & 15;
  const int cg = lane >> 4;
  const int st = wv & 1;
  const int p2 = wv >> 1;             // contributor index 0..3
  const int ntA = p2 * 2, ntB = ntA + 1;

  const int b = blockIdx.x >> 4;
  const int l0b = (blockIdx.x & 15) << 8;        // 256 l per block, 32 tiles of 8

  // ---- W fragments for ntA, ntB (h in [ntA*16, ntA*16+32)) ----
  bf16x8 wregA[16], wregB[16];
#pragma unroll
  for (int ks = 0; ks < 16; ++ks) {
    wregA[ks] = *(const bf16x8*)(wf + ((size_t)((ks * 8 + ntA) * 64 + lane)) * 4);
    wregB[ks] = *(const bf16x8*)(wf + ((size_t)((ks * 8 + ntB) * 64 + lane)) * 4);
  }

  const float qbrA = qb[ntA * 16 + r], qbrB = qb[ntB * 16 + r];
  const float vwrA = vw[ntA * 16 + r], vwrB = vw[ntB * 16 + r];

  // ---- staging helpers (chunk i: row = i*8+wv, d0 = (lane ^ (row&7))*8) ----
  f32x4 sv[8];
  auto issue_stage = [&](int l0) {
#pragma unroll
    for (int i = 0; i < 4; ++i) {
      int row = i * 8 + wv;
      int k = row & 3, pos = row >> 2;
      int d0 = (lane ^ (row & 7)) * 8;
      const float* p = hs + (((size_t)(k * BB + b)) * LL + l0 + pos) * DD + d0;
      sv[i * 2]     = *(const f32x4*)(p);
      sv[i * 2 + 1] = *(const f32x4*)(p + 4);
    }
  };
  auto write_stage = [&](char* dst) {
#pragma unroll
    for (int i = 0; i < 4; ++i) {
      u32x4 pk;
      pk.x = pack_bf16(sv[i * 2].x, sv[i * 2].y);
      pk.y = pack_bf16(sv[i * 2].z, sv[i * 2].w);
      pk.z = pack_bf16(sv[i * 2 + 1].x, sv[i * 2 + 1].y);
      pk.w = pack_bf16(sv[i * 2 + 1].z, sv[i * 2 + 1].w);
      *(u32x4*)(dst + i * 8192 + tid * 16) = pk;   // physical = logical ^ ((row&7)<<4)
    }
  };

  // ---- prologue: stage tile 0 ----
  issue_stage(l0b);
  write_stage(abuf);
  bar_lds();

  for (int t = 0; t < 32; ++t) {
    const int l0 = l0b + t * 8;
    char* cur = abuf + (t & 1) * 32768;
    char* nxt = abuf + ((t & 1) ^ 1) * 32768;

    // issue next tile's global loads NOW; consumed at tile end (write_stage)
    if (t < 31) issue_stage(l0 + 8);

    // ---- GEMM: 1 A-read + 2 MFMA per K-step ----
    f32x4 accA = {0.f, 0.f, 0.f, 0.f};
    f32x4 accB = {0.f, 0.f, 0.f, 0.f};
    const int arow = (st * 16 + r) * 1024;
    const int swz = (r & 7) << 4;
#pragma unroll
    for (int ks = 0; ks < 16; ++ks) {
      bf16x8 a = *(const bf16x8*)(cur + arow + ((ks * 64 + cg * 16) ^ swz));
      accA = __builtin_amdgcn_mfma_f32_16x16x32_bf16(a, wregA[ks], accA, 0, 0, 0);
      accB = __builtin_amdgcn_mfma_f32_16x16x32_bf16(a, wregB[ks], accB, 0, 0, 0);
    }

    // ---- epilogue A prefetch (data ready since prev B2; hides under scores) ----
    u32x4 uu[4];
#pragma unroll
    for (int k = 0; k < 4; ++k) {
      int row = wv * 4 + k;
      uu[k] = *(const u32x4*)(cur + row * 1024 + ((lane * 16) ^ ((row & 7) << 4)));
    }

    // ---- scores: ps[k] = sum_h vw[h]*tanh(z+qb[h]) over this wave's 32 h ----
    float ps[4];
#pragma unroll
    for (int j = 0; j < 4; ++j) {
      float zA = accA[j] + qbrA;
      zA = fminf(15.f, fmaxf(-15.f, zA));
      float eA = __expf(-2.f * zA);
      float thA = (1.f - eA) * __builtin_amdgcn_rcpf(1.f + eA);
      float zB = accB[j] + qbrB;
      zB = fminf(15.f, fmaxf(-15.f, zB));
      float eB = __expf(-2.f * zB);
      float thB = (1.f - eB) * __builtin_amdgcn_rcpf(1.f + eB);
      ps[j] = fmaf(vwrA, thA, vwrB * thB);
    }
    // reduce over the 16 lanes of each row group on the VALU pipe (DPP)
#pragma unroll
    for (int j = 0; j < 4; ++j) {
      ps[j] = dpp_shr_add<1>(ps[j]);
      ps[j] = dpp_shr_add<2>(ps[j]);
      ps[j] = dpp_shr_add<4>(ps[j]);
      ps[j] = dpp_shr_add<8>(ps[j]);
    }
    if (r == 15) {
      f32x4 v = {ps[0], ps[1], ps[2], ps[3]};
      spv[(st * 4 + cg) * 4 + p2] = v;   // pos = st*4+cg
    }
    bar_lds();                        // B1: spv published (loads stay in flight)

    // ---- per-thread softmax over k for pos = wv (4 broadcast reads) ----
    // mask dropped: uniform per-(b,l) shift is softmax-invariant
    float a0, a1, a2, a3;
    {
      f32x4 s = spv[wv * 4 + 0];
      s += spv[wv * 4 + 1];
      s += spv[wv * 4 + 2];
      s += spv[wv * 4 + 3];
      float mx = fmaxf(fmaxf(s.x, s.y), fmaxf(s.z, s.w));
      float e0 = __expf(s.x - mx), e1 = __expf(s.y - mx);
      float e2 = __expf(s.z - mx), e3 = __expf(s.w - mx);
      float inv = __builtin_amdgcn_rcpf(e0 + e1 + e2 + e3);
      a0 = e0 * inv; a1 = e1 * inv; a2 = e2 * inv; a3 = e3 * inv;
    }

    // ---- weighted sum: wave wv owns pos = wv; x[d] = sum_k a_k*hs_k[d] ----
    {
      float x[8];
#pragma unroll
      for (int j = 0; j < 8; ++j) x[j] = 0.f;
#pragma unroll
      for (int k = 0; k < 4; ++k) {
        float ak = k == 0 ? a0 : (k == 1 ? a1 : (k == 2 ? a2 : a3));
        u32x4 u = uu[k];
        x[0] = fmaf(ak, __uint_as_float(u.x << 16), x[0]);
        x[1] = fmaf(ak, __uint_as_float(u.x & 0xffff0000u), x[1]);
        x[2] = fmaf(ak, __uint_as_float(u.y << 16), x[2]);
        x[3] = fmaf(ak, __uint_as_float(u.y & 0xffff0000u), x[3]);
        x[4] = fmaf(ak, __uint_as_float(u.z << 16), x[4]);
        x[5] = fmaf(ak, __uint_as_float(u.z & 0xffff0000u), x[5]);
        x[6] = fmaf(ak, __uint_as_float(u.w << 16), x[6]);
        x[7] = fmaf(ak, __uint_as_float(u.w & 0xffff0000u), x[7]);
      }
      float* ob = out + (((size_t)b) * LL + l0 + wv) * DD + lane * 8;
      f32x4 o0 = {x[0], x[1], x[2], x[3]};
      f32x4 o1 = {x[4], x[5], x[6], x[7]};
      __builtin_nontemporal_store(o0, (f32x4*)ob);
      __builtin_nontemporal_store(o1, (f32x4*)(ob + 4));
    }

    // ---- publish next tile's buffer (waits only on sv's counted vmcnt) ----
    if (t < 31) write_stage(nxt);
    bar_lds();                        // B2: buffer published
  }
}

extern "C" void kernel_launch(void* const* d_in, const int* in_sizes, int n_in,
                              void* d_out, int out_size, void* d_ws, size_t ws_size,
                              hipStream_t stream) {
  const float* hs   = (const float*)d_in[0];
  // d_in[1] = mask (int32) — unused: softmax over k is invariant to the
  // per-(b,l) uniform -1e4 shift, so the mask cannot affect x.
  const float* ln_w = (const float*)d_in[2];
  const float* ln_b = (const float*)d_in[3];
  const float* v_w  = (const float*)d_in[4];
  const float* vq   = (const float*)d_in[5];
  float* out = (float*)d_out;

  unsigned int* wf = (unsigned int*)d_ws;          // 128KB fragment-ordered bf16 W_h
  float* qb = (float*)((char*)d_ws + 131072);      // 512B q_bias

  qbias_kernel<<<1, 128, 0, stream>>>(ln_w, ln_b, vq, qb);
  wf_kernel<<<32, 256, 0, stream>>>(ln_w, wf);
  agg_main<<<256, 512, 66048, stream>>>(hs, wf, qb, v_w, out);
}

// Round 8
// 147.248 us; speedup vs baseline: 1.0290x; 1.0285x over previous
//
#include <hip/hip_runtime.h>
#include <hip/hip_bf16.h>
#include <stdint.h>

// Problem constants
#define KK 4
#define BB 16
#define LL 4096
#define DD 512
#define HH 128

typedef __attribute__((ext_vector_type(8))) short bf16x8;
typedef __attribute__((ext_vector_type(4))) float f32x4;
typedef __attribute__((ext_vector_type(4))) unsigned int u32x4;

__device__ __forceinline__ unsigned int pack_bf16(float lo, float hi) {
  unsigned int a = __float_as_uint(lo);
  unsigned int b = __float_as_uint(hi);
  a = (a + 0x7FFFu + ((a >> 16) & 1u)) >> 16;   // RNE f32->bf16
  b = (b + 0x7FFFu + ((b >> 16) & 1u)) >> 16;
  return a | (b << 16);
}

// Raw barrier: LDS-ordering only (global loads stay in flight across it).
__device__ __forceinline__ void bar_lds() {
  __builtin_amdgcn_sched_barrier(0);
  asm volatile("s_waitcnt lgkmcnt(0)" ::: "memory");
  __builtin_amdgcn_s_barrier();
  __builtin_amdgcn_sched_barrier(0);
}

// x += row_shr:N (x) on the VALU pipe; rows of 16 lanes; 0-fill at row edge.
template <int N>
__device__ __forceinline__ float dpp_shr_add(float x) {
  int y = __builtin_amdgcn_update_dpp(0, __float_as_int(x), 0x110 | N, 0xF, 0xF,
                                      true);
  return x + __int_as_float(y);
}

// ---------------- kernel 0a: q_bias = W_q @ vq + ln_b ----------------
__global__ void qbias_kernel(const float* __restrict__ ln_w,
                             const float* __restrict__ ln_b,
                             const float* __restrict__ vq,
                             float* __restrict__ qb) {
  int h = threadIdx.x;
  if (h < HH) {
    float acc = ln_b[h];
    const float* wq = ln_w + (size_t)h * (DD + HH) + DD;
    for (int j = 0; j < HH; ++j) acc = fmaf(wq[j], vq[j], acc);
    qb[h] = acc;
  }
}

// ---------------- kernel 0b: W_h -> fragment-ordered bf16 (natural d) ----
// Chunk gid = (ks*8 + nt)*64 + lane holds 8 bf16 (MFMA B-fragment):
//   element j: W[nt*16 + (lane&15)][ks*32 + (lane>>4)*8 + j]
__global__ void wf_kernel(const float* __restrict__ ln_w,
                          unsigned int* __restrict__ wf) {
  int gid = blockIdx.x * 256 + threadIdx.x;   // 0..8191
  int ks = gid >> 9;
  int nt = (gid >> 6) & 7;
  int lane = gid & 63;
  int h = nt * 16 + (lane & 15);
  int d0 = ks * 32 + (lane >> 4) * 8;
  const float* src = ln_w + (size_t)h * (DD + HH) + d0;
  u32x4 v;
  v.x = pack_bf16(src[0], src[1]);
  v.y = pack_bf16(src[2], src[3]);
  v.z = pack_bf16(src[4], src[5]);
  v.w = pack_bf16(src[6], src[7]);
  *(u32x4*)(wf + (size_t)gid * 4) = v;
}

// ---------------- main fused kernel ----------------
// 256 blocks x 512 threads (1 block/CU, 8 waves), persistent over 32 tiles
// of 8 positions. A tile double-buffered as bf16 in LDS (2x32KB).
// DEPTH-2 read pipeline: two staging reg sets svA/svB; burst for tile t+2 is
// issued at tile t start, so write_stage(t+1) waits vmcnt(8) and the HBM
// read pipe always holds 1-2 bursts (the R4-R6 gap was the pipe emptying
// after each tile's single burst drained).
// Cell map (R5): wave wv -> nt = wv, M-subtiles st=0,1 (2 A-reads + 2 MFMA
// per K-step; W = 16 frags = 64 VGPR). A rows: row = pos*4 + k, XOR-swizzled
// by (row&7)<<4. C/D: pos = st*4 + (lane>>4), k = reg j.
__global__ __launch_bounds__(512) void agg_main(
    const float* __restrict__ hs, const unsigned int* __restrict__ wf,
    const float* __restrict__ qb, const float* __restrict__ vw,
    float* __restrict__ out) {
  extern __shared__ char smem[];
  char* buf0 = smem;                             // 32768 B
  char* buf1 = smem + 32768;                     // 32768 B
  f32x4* spv = (f32x4*)(smem + 65536);           // [8 pos][8 wv] (k in vec)

  const int tid = threadIdx.x;
  const int lane = tid & 63;
  const int wv = tid >> 6;            // 0..7
  const int r = lane & 15;
  const int cg = lane >> 4;

  const int b = blockIdx.x >> 4;
  const int l0b = (blockIdx.x & 15) << 8;        // 256 l per block, 32 tiles of 8

  // ---- W fragments for nt = wv (h in [wv*16, wv*16+16)) ----
  bf16x8 wreg[16];
#pragma unroll
  for (int ks = 0; ks < 16; ++ks)
    wreg[ks] = *(const bf16x8*)(wf + ((size_t)((ks * 8 + wv) * 64 + lane)) * 4);

  const float qbr = qb[wv * 16 + r];
  const float vwr = vw[wv * 16 + r];

  // ---- staging helpers (chunk i: row = i*8+wv) ----
  auto issue_stage = [&](int l0, f32x4* sv) {
#pragma unroll
    for (int i = 0; i < 4; ++i) {
      int row = i * 8 + wv;
      int k = row & 3, pos = row >> 2;
      int d0 = (lane ^ (row & 7)) * 8;
      const float* p = hs + (((size_t)(k * BB + b)) * LL + l0 + pos) * DD + d0;
      sv[i * 2]     = *(const f32x4*)(p);
      sv[i * 2 + 1] = *(const f32x4*)(p + 4);
    }
  };
  auto write_stage = [&](char* dst, const f32x4* sv) {
#pragma unroll
    for (int i = 0; i < 4; ++i) {
      u32x4 pk;
      pk.x = pack_bf16(sv[i * 2].x, sv[i * 2].y);
      pk.y = pack_bf16(sv[i * 2].z, sv[i * 2].w);
      pk.z = pack_bf16(sv[i * 2 + 1].x, sv[i * 2 + 1].y);
      pk.w = pack_bf16(sv[i * 2 + 1].z, sv[i * 2 + 1].w);
      *(u32x4*)(dst + i * 8192 + tid * 16) = pk;   // physical = logical ^ ((row&7)<<4)
    }
  };

  // One tile body: GEMM+epilogue on `cur` (tile at l0), then publish the
  // NEXT tile (regs svWr) into `nxt`; issue burst for tile l0+16 into svIs.
  auto body = [&](int l0, char* cur, char* nxt, const f32x4* svWr, f32x4* svIs,
                  bool doIssue, bool doWrite) {
    if (doIssue) issue_stage(l0 + 16, svIs);   // burst t+2: keeps read pipe fed

    // ---- GEMM: 2 A-reads + 2 MFMA per K-step (nt = wv, st = 0,1) ----
    f32x4 acc0 = {0.f, 0.f, 0.f, 0.f};
    f32x4 acc1 = {0.f, 0.f, 0.f, 0.f};
    const int swz = (r & 7) << 4;
#pragma unroll
    for (int ks = 0; ks < 16; ++ks) {
      int inner = (ks * 64 + cg * 16) ^ swz;
      bf16x8 a0 = *(const bf16x8*)(cur + r * 1024 + inner);
      bf16x8 a1 = *(const bf16x8*)(cur + (16 + r) * 1024 + inner);
      acc0 = __builtin_amdgcn_mfma_f32_16x16x32_bf16(a0, wreg[ks], acc0, 0, 0, 0);
      acc1 = __builtin_amdgcn_mfma_f32_16x16x32_bf16(a1, wreg[ks], acc1, 0, 0, 0);
    }

    // ---- scores: ps = vw[h]*tanh(z+qb[h]) summed over this wave's 16 h ----
    float ps[8];
#pragma unroll
    for (int st = 0; st < 2; ++st) {
      f32x4 acc = st ? acc1 : acc0;
#pragma unroll
      for (int j = 0; j < 4; ++j) {
        float z = acc[j] + qbr;
        z = fminf(15.f, fmaxf(-15.f, z));
        float e = __expf(-2.f * z);
        float th = (1.f - e) * __builtin_amdgcn_rcpf(1.f + e);
        ps[st * 4 + j] = vwr * th;
      }
    }
#pragma unroll
    for (int q = 0; q < 8; ++q) {
      ps[q] = dpp_shr_add<1>(ps[q]);
      ps[q] = dpp_shr_add<2>(ps[q]);
      ps[q] = dpp_shr_add<4>(ps[q]);
      ps[q] = dpp_shr_add<8>(ps[q]);
    }
    if (r == 15) {
      f32x4 v0 = {ps[0], ps[1], ps[2], ps[3]};
      f32x4 v1 = {ps[4], ps[5], ps[6], ps[7]};
      spv[(0 + cg) * 8 + wv] = v0;    // pos = cg
      spv[(4 + cg) * 8 + wv] = v1;    // pos = 4 + cg
    }
    bar_lds();                        // B1: spv published (loads in flight)

    // ---- softmax over k for pos = wv (8 broadcast reads) ----
    // mask dropped: uniform per-(b,l) shift is softmax-invariant
    float a0, a1, a2, a3;
    {
      f32x4 s = spv[wv * 8 + 0];
#pragma unroll
      for (int w2 = 1; w2 < 8; ++w2) s += spv[wv * 8 + w2];
      float mx = fmaxf(fmaxf(s.x, s.y), fmaxf(s.z, s.w));
      float e0 = __expf(s.x - mx), e1 = __expf(s.y - mx);
      float e2 = __expf(s.z - mx), e3 = __expf(s.w - mx);
      float inv = __builtin_amdgcn_rcpf(e0 + e1 + e2 + e3);
      a0 = e0 * inv; a1 = e1 * inv; a2 = e2 * inv; a3 = e3 * inv;
    }

    // ---- weighted sum: wave wv owns pos = wv (reads inline) ----
    {
      float x[8];
#pragma unroll
      for (int j = 0; j < 8; ++j) x[j] = 0.f;
#pragma unroll
      for (int k = 0; k < 4; ++k) {
        int row = wv * 4 + k;
        float ak = k == 0 ? a0 : (k == 1 ? a1 : (k == 2 ? a2 : a3));
        u32x4 u = *(const u32x4*)(cur + row * 1024 +
                                  ((lane * 16) ^ ((row & 7) << 4)));
        x[0] = fmaf(ak, __uint_as_float(u.x << 16), x[0]);
        x[1] = fmaf(ak, __uint_as_float(u.x & 0xffff0000u), x[1]);
        x[2] = fmaf(ak, __uint_as_float(u.y << 16), x[2]);
        x[3] = fmaf(ak, __uint_as_float(u.y & 0xffff0000u), x[3]);
        x[4] = fmaf(ak, __uint_as_float(u.z << 16), x[4]);
        x[5] = fmaf(ak, __uint_as_float(u.z & 0xffff0000u), x[5]);
        x[6] = fmaf(ak, __uint_as_float(u.w << 16), x[6]);
        x[7] = fmaf(ak, __uint_as_float(u.w & 0xffff0000u), x[7]);
      }
      float* ob = out + (((size_t)b) * LL + l0 + wv) * DD + lane * 8;
      f32x4 o0 = {x[0], x[1], x[2], x[3]};
      f32x4 o1 = {x[4], x[5], x[6], x[7]};
      __builtin_nontemporal_store(o0, (f32x4*)ob);
      __builtin_nontemporal_store(o1, (f32x4*)(ob + 4));
    }

    // ---- publish next tile (waits vmcnt(8): svIs stays outstanding) ----
    if (doWrite) write_stage(nxt, svWr);
    bar_lds();                        // B2: buffer published
  };

  f32x4 svA[8], svB[8];

  // ---- prologue: tile 0 staged; burst for tile 1 in flight (svA) ----
  issue_stage(l0b, svA);
  write_stage(buf0, svA);
  issue_stage(l0b + 8, svA);
  bar_lds();

  for (int tt = 0; tt < 16; ++tt) {
    const int l0 = l0b + tt * 16;
    const bool more = (tt < 15);
    // tile 2tt   : compute buf0; write tile 2tt+1 (svA); issue 2tt+2 -> svB
    body(l0, buf0, buf1, svA, svB, more, true);
    // tile 2tt+1 : compute buf1; write tile 2tt+2 (svB); issue 2tt+3 -> svA
    body(l0 + 8, buf1, buf0, svB, svA, more, more);
  }
}

extern "C" void kernel_launch(void* const* d_in, const int* in_sizes, int n_in,
                              void* d_out, int out_size, void* d_ws, size_t ws_size,
                              hipStream_t stream) {
  const float* hs   = (const float*)d_in[0];
  // d_in[1] = mask (int32) — unused: softmax over k is invariant to the
  // per-(b,l) uniform -1e4 shift, so the mask cannot affect x.
  const float* ln_w = (const float*)d_in[2];
  const float* ln_b = (const float*)d_in[3];
  const float* v_w  = (const float*)d_in[4];
  const float* vq   = (const float*)d_in[5];
  float* out = (float*)d_out;

  unsigned int* wf = (unsigned int*)d_ws;          // 128KB fragment-ordered bf16 W_h
  float* qb = (float*)((char*)d_ws + 131072);      // 512B q_bias

  qbias_kernel<<<1, 128, 0, stream>>>(ln_w, ln_b, vq, qb);
  wf_kernel<<<32, 256, 0, stream>>>(ln_w, wf);
  agg_main<<<256, 512, 66560, stream>>>(hs, wf, qb, v_w, out);
}